// Round 2
// baseline (532.789 us; speedup 1.0000x reference)
//
#include <hip/hip_runtime.h>
#include <hip/hip_bf16.h>

// Problem constants (fixed by the reference)
#define BB 2
#define NN 2048
#define KE 48     // neighbors per node
#define CC 128
#define FFD 512
#define K3 384    // 3*C

// bf16 MFMA fragment types (guide §3, HW-verified m89/m91/m92)
typedef short sx8 __attribute__((ext_vector_type(8)));   // 8 bf16 in 4 VGPRs
typedef float fx4 __attribute__((ext_vector_type(4)));   // 4 fp32 acc

__device__ __forceinline__ short f2bs(float f) {
    __bf16 h = (__bf16)f;            // RNE fp32->bf16
    return __builtin_bit_cast(short, h);
}

__device__ __forceinline__ float gelu_f(float x) {
    // exact GELU (approximate=False): 0.5*x*(1+erf(x/sqrt(2)))
    return 0.5f * x * (1.0f + erff(x * 0.7071067811865475f));
}

// load 8 consecutive fp32 (32B aligned) and convert to bf16x8 (as short8)
__device__ __forceinline__ sx8 cvt8f(const float* p) {
    float4 a = *(const float4*)p;
    float4 b = *(const float4*)(p + 4);
    sx8 r;
    r[0] = f2bs(a.x); r[1] = f2bs(a.y); r[2] = f2bs(a.z); r[3] = f2bs(a.w);
    r[4] = f2bs(b.x); r[5] = f2bs(b.y); r[6] = f2bs(b.z); r[7] = f2bs(b.w);
    return r;
}

// ---------------------------------------------------------------------------
// Transpose + fp32->bf16 convert the 6 edge-MLP weights into ws.
// Output layouts: WT[n][k] so B-fragments are contiguous in k.
// Offsets (bf16 elements): W1T@0(128x384), W2T@49152(128x128), W3T@65536,
// W11T@81920(128x384), W12T@131072, W13T@147456; total 163840 elems (320KB).
// ---------------------------------------------------------------------------
__global__ void prep_weights(const float* __restrict__ W1, const float* __restrict__ W2,
                             const float* __restrict__ W3, const float* __restrict__ W11,
                             const float* __restrict__ W12, const float* __restrict__ W13,
                             short* __restrict__ wt) {
    int i = blockIdx.x * 256 + threadIdx.x;  // grid covers exactly 163840
    const float* src;
    short* dst;
    int R, local;
    if (i < 49152)       { src = W1;  dst = wt;          R = 384; local = i; }
    else if (i < 65536)  { src = W2;  dst = wt + 49152;  R = 128; local = i - 49152; }
    else if (i < 81920)  { src = W3;  dst = wt + 65536;  R = 128; local = i - 65536; }
    else if (i < 131072) { src = W11; dst = wt + 81920;  R = 384; local = i - 81920; }
    else if (i < 147456) { src = W12; dst = wt + 131072; R = 128; local = i - 131072; }
    else                 { src = W13; dst = wt + 147456; R = 128; local = i - 147456; }
    int c = local / R;
    int r = local - c * R;
    dst[local] = f2bs(src[r * 128 + c]);  // WT[c][r] = W[r][c]
}

// ---------------------------------------------------------------------------
// Edge MLP pass. One block (256 thr = 4 waves) per node (b,n).
// PASS 1: msg = MLP(concat) ; dh = sum_k(mask*msg)/30 ; hv1 = LN1(hV+dh) -> hv1_out (fp32)
// PASS 2: msg = MLP(concat) ; hE_out = LN3(hE + msg)
// MFMA 16x16x32 bf16, M=48 (3 mtiles), N=128 (2 ntiles/wave), K=384/128/128.
// A layout: A[m=lane&15][k=(lane>>4)*8+j]; C/D: col=lane&15, row=(lane>>4)*4+reg.
// ---------------------------------------------------------------------------
template <int PASS>
__global__ __launch_bounds__(256, 3) void edge_pass(
    const float* __restrict__ hVsrc, const float* __restrict__ hE,
    const int* __restrict__ Eidx,
    const short* __restrict__ WaT, const float* __restrict__ Wab,
    const short* __restrict__ WbT, const float* __restrict__ Wbb,
    const short* __restrict__ WcT, const float* __restrict__ Wcb,
    const float* __restrict__ mask_att, float* __restrict__ hv1_out,
    const float* __restrict__ gamma, const float* __restrict__ beta,
    float* __restrict__ hE_out) {
    // A0 tile 48x392 bf16 (37632B); aliased by S 48x132 fp32 (25344B) in PASS2 epilogue
    __shared__ __align__(16) unsigned char smem_raw[48 * 392 * 2];
    __shared__ __align__(16) short Xs[48 * 136];
    __shared__ float dh_part[4 * 128];
    __shared__ float red[4];

    short* A0 = (short*)smem_raw;
    float* S = (float*)smem_raw;

    const int tid = threadIdx.x;
    const int bn  = blockIdx.x;       // b*N+n
    const int bb  = bn >> 11;         // batch (N=2048)
    const int wave = tid >> 6, lane = tid & 63, q = lane >> 4, m16 = lane & 15;
    const int col0 = wave * 32 + m16; // ntile 2*wave
    const int col1 = col0 + 16;       // ntile 2*wave+1

    // ---- stage A0 = [ctr | hE | nbr] as bf16 ----
    {
        const float* ctr = hVsrc + bn * CC;
        for (int i = tid; i < 48 * 16; i += 256) {
            int row = i >> 4, seg = i & 15;
            *(sx8*)(A0 + row * 392 + seg * 8) = cvt8f(ctr + seg * 8);
        }
        for (int i = tid; i < 48 * 16; i += 256) {
            int row = i >> 4, seg = i & 15;
            *(sx8*)(A0 + row * 392 + 128 + seg * 8) = cvt8f(hE + (bn * KE + row) * CC + seg * 8);
        }
        for (int i = tid; i < 48 * 16; i += 256) {
            int row = i >> 4, seg = i & 15;
            int idx = Eidx[bn * KE + row];
            *(sx8*)(A0 + row * 392 + 256 + seg * 8) = cvt8f(hVsrc + (bb * NN + idx) * CC + seg * 8);
        }
    }
    __syncthreads();

    // ---- GEMM1: [48x384] @ W1T' -> gelu -> Xs ----
    fx4 acc[3][2];
#pragma unroll
    for (int mt = 0; mt < 3; ++mt)
#pragma unroll
        for (int nt = 0; nt < 2; ++nt)
#pragma unroll
            for (int r = 0; r < 4; ++r) acc[mt][nt][r] = 0.0f;

#pragma unroll
    for (int kk = 0; kk < 12; ++kk) {
        sx8 bf0 = *(const sx8*)(WaT + col0 * K3 + kk * 32 + q * 8);
        sx8 bf1 = *(const sx8*)(WaT + col1 * K3 + kk * 32 + q * 8);
#pragma unroll
        for (int mt = 0; mt < 3; ++mt) {
            sx8 af = *(const sx8*)(A0 + (mt * 16 + m16) * 392 + kk * 32 + q * 8);
            acc[mt][0] = __builtin_amdgcn_mfma_f32_16x16x32_bf16(af, bf0, acc[mt][0], 0, 0, 0);
            acc[mt][1] = __builtin_amdgcn_mfma_f32_16x16x32_bf16(af, bf1, acc[mt][1], 0, 0, 0);
        }
    }
    {
        float ba0 = Wab[col0], ba1 = Wab[col1];
#pragma unroll
        for (int mt = 0; mt < 3; ++mt)
#pragma unroll
            for (int r = 0; r < 4; ++r) {
                int row = mt * 16 + q * 4 + r;
                Xs[row * 136 + col0] = f2bs(gelu_f(acc[mt][0][r] + ba0));
                Xs[row * 136 + col1] = f2bs(gelu_f(acc[mt][1][r] + ba1));
            }
    }
    __syncthreads();

    // ---- GEMM2: [48x128] @ WbT' -> gelu -> Xs ----
    fx4 acc2[3][2];
#pragma unroll
    for (int mt = 0; mt < 3; ++mt)
#pragma unroll
        for (int nt = 0; nt < 2; ++nt)
#pragma unroll
            for (int r = 0; r < 4; ++r) acc2[mt][nt][r] = 0.0f;

#pragma unroll
    for (int kk = 0; kk < 4; ++kk) {
        sx8 bf0 = *(const sx8*)(WbT + col0 * CC + kk * 32 + q * 8);
        sx8 bf1 = *(const sx8*)(WbT + col1 * CC + kk * 32 + q * 8);
#pragma unroll
        for (int mt = 0; mt < 3; ++mt) {
            sx8 af = *(const sx8*)(Xs + (mt * 16 + m16) * 136 + kk * 32 + q * 8);
            acc2[mt][0] = __builtin_amdgcn_mfma_f32_16x16x32_bf16(af, bf0, acc2[mt][0], 0, 0, 0);
            acc2[mt][1] = __builtin_amdgcn_mfma_f32_16x16x32_bf16(af, bf1, acc2[mt][1], 0, 0, 0);
        }
    }
    __syncthreads();  // all waves done reading X1
    {
        float bb0 = Wbb[col0], bb1 = Wbb[col1];
#pragma unroll
        for (int mt = 0; mt < 3; ++mt)
#pragma unroll
            for (int r = 0; r < 4; ++r) {
                int row = mt * 16 + q * 4 + r;
                Xs[row * 136 + col0] = f2bs(gelu_f(acc2[mt][0][r] + bb0));
                Xs[row * 136 + col1] = f2bs(gelu_f(acc2[mt][1][r] + bb1));
            }
    }
    __syncthreads();

    // ---- GEMM3: [48x128] @ WcT' (bias in epilogue) ----
    fx4 acc3[3][2];
#pragma unroll
    for (int mt = 0; mt < 3; ++mt)
#pragma unroll
        for (int nt = 0; nt < 2; ++nt)
#pragma unroll
            for (int r = 0; r < 4; ++r) acc3[mt][nt][r] = 0.0f;

#pragma unroll
    for (int kk = 0; kk < 4; ++kk) {
        sx8 bf0 = *(const sx8*)(WcT + col0 * CC + kk * 32 + q * 8);
        sx8 bf1 = *(const sx8*)(WcT + col1 * CC + kk * 32 + q * 8);
#pragma unroll
        for (int mt = 0; mt < 3; ++mt) {
            sx8 af = *(const sx8*)(Xs + (mt * 16 + m16) * 136 + kk * 32 + q * 8);
            acc3[mt][0] = __builtin_amdgcn_mfma_f32_16x16x32_bf16(af, bf0, acc3[mt][0], 0, 0, 0);
            acc3[mt][1] = __builtin_amdgcn_mfma_f32_16x16x32_bf16(af, bf1, acc3[mt][1], 0, 0, 0);
        }
    }

    float bc0 = Wcb[col0], bc1 = Wcb[col1];

    if constexpr (PASS == 1) {
        // masked sum over the 48 edge rows -> dh[col]
        float ps0 = 0.f, ps1 = 0.f;
#pragma unroll
        for (int mt = 0; mt < 3; ++mt)
#pragma unroll
            for (int r = 0; r < 4; ++r) {
                int row = mt * 16 + q * 4 + r;
                float m = mask_att[bn * KE + row];
                ps0 += m * (acc3[mt][0][r] + bc0);
                ps1 += m * (acc3[mt][1][r] + bc1);
            }
        dh_part[q * 128 + col0] = ps0;
        dh_part[q * 128 + col1] = ps1;
        __syncthreads();
        float val = 0.f;
        if (tid < 128) {
            float dh = dh_part[tid] + dh_part[128 + tid] + dh_part[256 + tid] + dh_part[384 + tid];
            val = hVsrc[bn * CC + tid] + dh * (1.0f / 30.0f);
            float s1 = val, s2 = val * val;
#pragma unroll
            for (int m = 32; m >= 1; m >>= 1) {
                s1 += __shfl_xor(s1, m);
                s2 += __shfl_xor(s2, m);
            }
            if ((tid & 63) == 0) {
                red[(tid >> 6) * 2]     = s1;
                red[(tid >> 6) * 2 + 1] = s2;
            }
        }
        __syncthreads();
        if (tid < 128) {
            float mean = (red[0] + red[2]) * (1.0f / 128.0f);
            float var  = (red[1] + red[3]) * (1.0f / 128.0f) - mean * mean;
            float rstd = rsqrtf(fmaxf(var, 0.0f) + 1e-5f);
            hv1_out[bn * CC + tid] = gamma[tid] * (val - mean) * rstd + beta[tid];
        }
    } else {
        // S = hE + msg (fp32, aliases A0 -- safe: A0 unread since GEMM1 barrier)
#pragma unroll
        for (int mt = 0; mt < 3; ++mt)
#pragma unroll
            for (int r = 0; r < 4; ++r) {
                int row = mt * 16 + q * 4 + r;
                S[row * 132 + col0] = hE[(bn * KE + row) * CC + col0] + acc3[mt][0][r] + bc0;
                S[row * 132 + col1] = hE[(bn * KE + row) * CC + col1] + acc3[mt][1][r] + bc1;
            }
        __syncthreads();
        // per-edge-row LayerNorm; 8 groups of 32 lanes, 6 rows each
        int g = tid >> 5, l32 = tid & 31;
        for (int r = g; r < 48; r += 8) {
            float x0 = S[r * 132 + l32];
            float x1 = S[r * 132 + l32 + 32];
            float x2 = S[r * 132 + l32 + 64];
            float x3 = S[r * 132 + l32 + 96];
            float s1 = x0 + x1 + x2 + x3;
            float s2 = x0 * x0 + x1 * x1 + x2 * x2 + x3 * x3;
#pragma unroll
            for (int m = 16; m >= 1; m >>= 1) {
                s1 += __shfl_xor(s1, m, 32);
                s2 += __shfl_xor(s2, m, 32);
            }
            float mean = s1 * (1.0f / 128.0f);
            float var  = s2 * (1.0f / 128.0f) - mean * mean;
            float rstd = rsqrtf(fmaxf(var, 0.0f) + 1e-5f);
            float* orow = hE_out + (bn * KE + r) * CC;
            orow[l32]      = gamma[l32] * (x0 - mean) * rstd + beta[l32];
            orow[l32 + 32] = gamma[l32 + 32] * (x1 - mean) * rstd + beta[l32 + 32];
            orow[l32 + 64] = gamma[l32 + 64] * (x2 - mean) * rstd + beta[l32 + 64];
            orow[l32 + 96] = gamma[l32 + 96] * (x3 - mean) * rstd + beta[l32 + 96];
        }
    }
}

// ---------------------------------------------------------------------------
// Per-node FFN: hv2 = maskV * LN2(hv1 + GELU(hv1@Win+bin)@Wout+bout)
// 128 threads per node; reads hv1 from d_out h_V region and overwrites it
// (own node's row only -> no cross-block hazard).
// ---------------------------------------------------------------------------
__global__ __launch_bounds__(128) void ffn_kernel(
    float* __restrict__ hv, const float* __restrict__ Win,
    const float* __restrict__ Winb, const float* __restrict__ Wout,
    const float* __restrict__ Woutb, const float* __restrict__ g2,
    const float* __restrict__ b2, const float* __restrict__ maskV,
    const float* __restrict__ /*unused*/) {
    __shared__ float hv_s[128];
    __shared__ float hid_s[512];
    __shared__ float red[4];
    int tid = threadIdx.x, bn = blockIdx.x;
    hv_s[tid] = hv[bn * CC + tid];
    __syncthreads();
    float a0 = 0.f, a1 = 0.f, a2 = 0.f, a3 = 0.f;
#pragma unroll 4
    for (int c = 0; c < 128; ++c) {
        float h = hv_s[c];
        const float* wr = Win + c * FFD;
        a0 += h * wr[tid];
        a1 += h * wr[tid + 128];
        a2 += h * wr[tid + 256];
        a3 += h * wr[tid + 384];
    }
    hid_s[tid]       = gelu_f(a0 + Winb[tid]);
    hid_s[tid + 128] = gelu_f(a1 + Winb[tid + 128]);
    hid_s[tid + 256] = gelu_f(a2 + Winb[tid + 256]);
    hid_s[tid + 384] = gelu_f(a3 + Winb[tid + 384]);
    __syncthreads();
    float o = 0.f;
#pragma unroll 8
    for (int f = 0; f < 512; ++f) o += hid_s[f] * Wout[f * CC + tid];
    float val = hv_s[tid] + o + Woutb[tid];
    float s1 = val, s2 = val * val;
#pragma unroll
    for (int m = 32; m >= 1; m >>= 1) {
        s1 += __shfl_xor(s1, m);
        s2 += __shfl_xor(s2, m);
    }
    if ((tid & 63) == 0) {
        red[(tid >> 6) * 2]     = s1;
        red[(tid >> 6) * 2 + 1] = s2;
    }
    __syncthreads();
    float mean = (red[0] + red[2]) * (1.0f / 128.0f);
    float var  = (red[1] + red[3]) * (1.0f / 128.0f) - mean * mean;
    float rstd = rsqrtf(fmaxf(var, 0.0f) + 1e-5f);
    float hv2  = g2[tid] * (val - mean) * rstd + b2[tid];
    hv2 *= maskV[bn];
    hv[bn * CC + tid] = hv2;
}

extern "C" void kernel_launch(void* const* d_in, const int* in_sizes, int n_in,
                              void* d_out, int out_size, void* d_ws, size_t ws_size,
                              hipStream_t stream) {
    (void)in_sizes; (void)n_in; (void)out_size; (void)ws_size;
    const float* hV    = (const float*)d_in[0];
    const float* hE    = (const float*)d_in[1];
    const int*   Eidx  = (const int*)d_in[2];
    const float* maskV = (const float*)d_in[3];
    const float* maskA = (const float*)d_in[4];
    const float* W1w  = (const float*)d_in[5];
    const float* W1b  = (const float*)d_in[6];
    const float* W2w  = (const float*)d_in[7];
    const float* W2b  = (const float*)d_in[8];
    const float* W3w  = (const float*)d_in[9];
    const float* W3b  = (const float*)d_in[10];
    const float* W11w = (const float*)d_in[11];
    const float* W11b = (const float*)d_in[12];
    const float* W12w = (const float*)d_in[13];
    const float* W12b = (const float*)d_in[14];
    const float* W13w = (const float*)d_in[15];
    const float* W13b = (const float*)d_in[16];
    const float* Winw = (const float*)d_in[17];
    const float* Winb = (const float*)d_in[18];
    const float* Woutw = (const float*)d_in[19];
    const float* Woutb = (const float*)d_in[20];
    const float* g1 = (const float*)d_in[21];
    const float* b1 = (const float*)d_in[22];
    const float* g2 = (const float*)d_in[23];
    const float* b2 = (const float*)d_in[24];
    const float* g3 = (const float*)d_in[25];
    const float* b3 = (const float*)d_in[26];

    short* wt   = (short*)d_ws;                 // 163840 bf16 = 327680 B
    float* outV = (float*)d_out;                // h_V region [4096,128]
    float* outE = outV + (size_t)BB * NN * CC;  // h_E region [4096,48,128]

    prep_weights<<<640, 256, 0, stream>>>(W1w, W2w, W3w, W11w, W12w, W13w, wt);
    edge_pass<1><<<BB * NN, 256, 0, stream>>>(hV, hE, Eidx,
                                              wt, W1b, wt + 49152, W2b, wt + 65536, W3b,
                                              maskA, outV, g1, b1, nullptr);
    ffn_kernel<<<BB * NN, 128, 0, stream>>>(outV, Winw, Winb, Woutw, Woutb, g2, b2, maskV, nullptr);
    edge_pass<2><<<BB * NN, 256, 0, stream>>>(outV, hE, Eidx,
                                              wt + 81920, W11b, wt + 131072, W12b, wt + 147456, W13b,
                                              nullptr, nullptr, g3, b3, outE);
}

// Round 4
// 436.979 us; speedup vs baseline: 1.2193x; 1.2193x over previous
//
#include <hip/hip_runtime.h>
#include <hip/hip_bf16.h>

// Problem constants (fixed by the reference)
#define BB 2
#define NN 2048
#define KE 48     // neighbors per node
#define CC 128
#define FFD 512
#define K3 384    // 3*C

// bf16 MFMA fragment types (guide §3, HW-verified m89/m91/m92)
typedef short sx8 __attribute__((ext_vector_type(8)));   // 8 bf16 in 4 VGPRs
typedef float fx4 __attribute__((ext_vector_type(4)));   // 4 fp32 acc

__device__ __forceinline__ short f2bs(float f) {
    __bf16 h = (__bf16)f;            // RNE fp32->bf16
    return __builtin_bit_cast(short, h);
}

// Fast exact-quality GELU: erf via Abramowitz-Stegun 7.1.26, |err|<1.5e-7.
// Branch-free (~12 VALU: 1 v_exp_f32, 1 v_rcp_f32, rest FMA) vs libm erff
// (~40+ inst with divergent range branch). Validated R3 (output 0 passed).
__device__ __forceinline__ float gelu_f(float x) {
    float z = fabsf(x) * 0.70710678118654752f;
    float e = __expf(-z * z);
    float t = __builtin_amdgcn_rcpf(fmaf(0.3275911f, z, 1.0f));
    float poly = t * fmaf(t, fmaf(t, fmaf(t, fmaf(t, 1.061405429f, -1.453152027f),
                                          1.421413741f), -0.284496736f), 0.254829592f);
    float erf = 1.0f - poly * e;
    float phi = fmaf(copysignf(erf, x), 0.5f, 0.5f);
    return x * phi;
}

// load 8 consecutive fp32 (32B aligned) and convert to bf16x8 (as short8)
__device__ __forceinline__ sx8 cvt8f(const float* p) {
    float4 a = *(const float4*)p;
    float4 b = *(const float4*)(p + 4);
    sx8 r;
    r[0] = f2bs(a.x); r[1] = f2bs(a.y); r[2] = f2bs(a.z); r[3] = f2bs(a.w);
    r[4] = f2bs(b.x); r[5] = f2bs(b.y); r[6] = f2bs(b.z); r[7] = f2bs(b.w);
    return r;
}

// ---------------------------------------------------------------------------
// Transpose + fp32->bf16 convert the 8 weight matrices into ws.
// Output layouts: WT[n][k] so B-fragments are contiguous in k.
// bf16-elem offsets: W1T@0(128x384) W2T@49152(128x128) W3T@65536
// W11T@81920(128x384) W12T@131072 W13T@147456 WinT@163840(512x128)
// WoutT@229376(128x512); total 294912 elems (576KB ws).
// ---------------------------------------------------------------------------
__global__ void prep_weights(const float* __restrict__ W1, const float* __restrict__ W2,
                             const float* __restrict__ W3, const float* __restrict__ W11,
                             const float* __restrict__ W12, const float* __restrict__ W13,
                             const float* __restrict__ Win, const float* __restrict__ Wout,
                             short* __restrict__ wt) {
    int i = blockIdx.x * 256 + threadIdx.x;  // grid covers exactly 294912
    const float* src;
    short* dst;
    int R, S, local;   // R = inner (k) extent of WT; S = row stride of source
    if (i < 49152)       { src = W1;   dst = wt;          R = 384; S = 128; local = i; }
    else if (i < 65536)  { src = W2;   dst = wt + 49152;  R = 128; S = 128; local = i - 49152; }
    else if (i < 81920)  { src = W3;   dst = wt + 65536;  R = 128; S = 128; local = i - 65536; }
    else if (i < 131072) { src = W11;  dst = wt + 81920;  R = 384; S = 128; local = i - 81920; }
    else if (i < 147456) { src = W12;  dst = wt + 131072; R = 128; S = 128; local = i - 131072; }
    else if (i < 163840) { src = W13;  dst = wt + 147456; R = 128; S = 128; local = i - 147456; } // R3 bug: was i-163840
    else if (i < 229376) { src = Win;  dst = wt + 163840; R = 128; S = 512; local = i - 163840; }
    else                 { src = Wout; dst = wt + 229376; R = 512; S = 128; local = i - 229376; }
    int c = local / R;
    int r = local - c * R;
    dst[local] = f2bs(src[r * S + c]);  // WT[c][r] = W[r][c]
}

// ---------------------------------------------------------------------------
// Edge MLP pass. One block (256 thr = 4 waves) per node (b,n).
// PASS 1: msg = MLP(concat) ; dh = sum_k(mask*msg)/30 ; hv1 = LN1(hV+dh) -> hv1_out (fp32)
// PASS 2: msg = MLP(concat) ; hE_out = LN3(hE + msg)
// MFMA 16x16x32 bf16, M=48 (3 mtiles), N=128 (2 ntiles/wave), K=384/128/128.
// A layout: A[m=lane&15][k=(lane>>4)*8+j]; C/D: col=lane&15, row=(lane>>4)*4+reg.
// ---------------------------------------------------------------------------
template <int PASS>
__global__ __launch_bounds__(256, 3) void edge_pass(
    const float* __restrict__ hVsrc, const float* __restrict__ hE,
    const int* __restrict__ Eidx,
    const short* __restrict__ WaT, const float* __restrict__ Wab,
    const short* __restrict__ WbT, const float* __restrict__ Wbb,
    const short* __restrict__ WcT, const float* __restrict__ Wcb,
    const float* __restrict__ mask_att, float* __restrict__ hv1_out,
    const float* __restrict__ gamma, const float* __restrict__ beta,
    float* __restrict__ hE_out) {
    // A0 tile 48x392 bf16 (37632B); aliased by S 48x132 fp32 (25344B) in PASS2 epilogue
    __shared__ __align__(16) unsigned char smem_raw[48 * 392 * 2];
    __shared__ __align__(16) short Xs[48 * 136];
    __shared__ float dh_part[4 * 128];
    __shared__ float red[4];

    short* A0 = (short*)smem_raw;
    float* S = (float*)smem_raw;

    const int tid = threadIdx.x;
    const int bn  = blockIdx.x;       // b*N+n
    const int bb  = bn >> 11;         // batch (N=2048)
    const int wave = tid >> 6, lane = tid & 63, q = lane >> 4, m16 = lane & 15;
    const int col0 = wave * 32 + m16; // ntile 2*wave
    const int col1 = col0 + 16;       // ntile 2*wave+1

    // ---- stage A0 = [ctr | hE | nbr] as bf16 ----
    {
        const float* ctr = hVsrc + bn * CC;
        for (int i = tid; i < 48 * 16; i += 256) {
            int row = i >> 4, seg = i & 15;
            *(sx8*)(A0 + row * 392 + seg * 8) = cvt8f(ctr + seg * 8);
        }
        for (int i = tid; i < 48 * 16; i += 256) {
            int row = i >> 4, seg = i & 15;
            *(sx8*)(A0 + row * 392 + 128 + seg * 8) = cvt8f(hE + (bn * KE + row) * CC + seg * 8);
        }
        for (int i = tid; i < 48 * 16; i += 256) {
            int row = i >> 4, seg = i & 15;
            int idx = Eidx[bn * KE + row];
            *(sx8*)(A0 + row * 392 + 256 + seg * 8) = cvt8f(hVsrc + (bb * NN + idx) * CC + seg * 8);
        }
    }
    __syncthreads();

    // ---- GEMM1: [48x384] @ W1T' -> gelu -> Xs ----
    fx4 acc[3][2];
#pragma unroll
    for (int mt = 0; mt < 3; ++mt)
#pragma unroll
        for (int nt = 0; nt < 2; ++nt)
#pragma unroll
            for (int r = 0; r < 4; ++r) acc[mt][nt][r] = 0.0f;

#pragma unroll
    for (int half = 0; half < 2; ++half) {
        sx8 b0[6], b1[6];
#pragma unroll
        for (int kk = 0; kk < 6; ++kk) {
            b0[kk] = *(const sx8*)(WaT + col0 * K3 + (half * 6 + kk) * 32 + q * 8);
            b1[kk] = *(const sx8*)(WaT + col1 * K3 + (half * 6 + kk) * 32 + q * 8);
        }
#pragma unroll
        for (int kk = 0; kk < 6; ++kk) {
#pragma unroll
            for (int mt = 0; mt < 3; ++mt) {
                sx8 af = *(const sx8*)(A0 + (mt * 16 + m16) * 392 + (half * 6 + kk) * 32 + q * 8);
                acc[mt][0] = __builtin_amdgcn_mfma_f32_16x16x32_bf16(af, b0[kk], acc[mt][0], 0, 0, 0);
                acc[mt][1] = __builtin_amdgcn_mfma_f32_16x16x32_bf16(af, b1[kk], acc[mt][1], 0, 0, 0);
            }
        }
    }
    {
        float ba0 = Wab[col0], ba1 = Wab[col1];
#pragma unroll
        for (int mt = 0; mt < 3; ++mt)
#pragma unroll
            for (int r = 0; r < 4; ++r) {
                int row = mt * 16 + q * 4 + r;
                Xs[row * 136 + col0] = f2bs(gelu_f(acc[mt][0][r] + ba0));
                Xs[row * 136 + col1] = f2bs(gelu_f(acc[mt][1][r] + ba1));
            }
    }
    __syncthreads();

    // ---- GEMM2: [48x128] @ WbT' -> gelu -> Xs ----
    fx4 acc2[3][2];
#pragma unroll
    for (int mt = 0; mt < 3; ++mt)
#pragma unroll
        for (int nt = 0; nt < 2; ++nt)
#pragma unroll
            for (int r = 0; r < 4; ++r) acc2[mt][nt][r] = 0.0f;

    {
        sx8 b0[4], b1[4];
#pragma unroll
        for (int kk = 0; kk < 4; ++kk) {
            b0[kk] = *(const sx8*)(WbT + col0 * CC + kk * 32 + q * 8);
            b1[kk] = *(const sx8*)(WbT + col1 * CC + kk * 32 + q * 8);
        }
#pragma unroll
        for (int kk = 0; kk < 4; ++kk) {
#pragma unroll
            for (int mt = 0; mt < 3; ++mt) {
                sx8 af = *(const sx8*)(Xs + (mt * 16 + m16) * 136 + kk * 32 + q * 8);
                acc2[mt][0] = __builtin_amdgcn_mfma_f32_16x16x32_bf16(af, b0[kk], acc2[mt][0], 0, 0, 0);
                acc2[mt][1] = __builtin_amdgcn_mfma_f32_16x16x32_bf16(af, b1[kk], acc2[mt][1], 0, 0, 0);
            }
        }
    }
    __syncthreads();  // all waves done reading X1
    {
        float bb0 = Wbb[col0], bb1 = Wbb[col1];
#pragma unroll
        for (int mt = 0; mt < 3; ++mt)
#pragma unroll
            for (int r = 0; r < 4; ++r) {
                int row = mt * 16 + q * 4 + r;
                Xs[row * 136 + col0] = f2bs(gelu_f(acc2[mt][0][r] + bb0));
                Xs[row * 136 + col1] = f2bs(gelu_f(acc2[mt][1][r] + bb1));
            }
    }
    __syncthreads();

    // ---- GEMM3: [48x128] @ WcT' (bias in epilogue) ----
    fx4 acc3[3][2];
#pragma unroll
    for (int mt = 0; mt < 3; ++mt)
#pragma unroll
        for (int nt = 0; nt < 2; ++nt)
#pragma unroll
            for (int r = 0; r < 4; ++r) acc3[mt][nt][r] = 0.0f;

    {
        sx8 b0[4], b1[4];
#pragma unroll
        for (int kk = 0; kk < 4; ++kk) {
            b0[kk] = *(const sx8*)(WcT + col0 * CC + kk * 32 + q * 8);
            b1[kk] = *(const sx8*)(WcT + col1 * CC + kk * 32 + q * 8);
        }
#pragma unroll
        for (int kk = 0; kk < 4; ++kk) {
#pragma unroll
            for (int mt = 0; mt < 3; ++mt) {
                sx8 af = *(const sx8*)(Xs + (mt * 16 + m16) * 136 + kk * 32 + q * 8);
                acc3[mt][0] = __builtin_amdgcn_mfma_f32_16x16x32_bf16(af, b0[kk], acc3[mt][0], 0, 0, 0);
                acc3[mt][1] = __builtin_amdgcn_mfma_f32_16x16x32_bf16(af, b1[kk], acc3[mt][1], 0, 0, 0);
            }
        }
    }

    float bc0 = Wcb[col0], bc1 = Wcb[col1];

    if constexpr (PASS == 1) {
        // masked sum over the 48 edge rows -> dh[col]
        float ps0 = 0.f, ps1 = 0.f;
#pragma unroll
        for (int mt = 0; mt < 3; ++mt)
#pragma unroll
            for (int r = 0; r < 4; ++r) {
                int row = mt * 16 + q * 4 + r;
                float m = mask_att[bn * KE + row];
                ps0 += m * (acc3[mt][0][r] + bc0);
                ps1 += m * (acc3[mt][1][r] + bc1);
            }
        dh_part[q * 128 + col0] = ps0;
        dh_part[q * 128 + col1] = ps1;
        __syncthreads();
        float val = 0.f;
        if (tid < 128) {
            float dh = dh_part[tid] + dh_part[128 + tid] + dh_part[256 + tid] + dh_part[384 + tid];
            val = hVsrc[bn * CC + tid] + dh * (1.0f / 30.0f);
            float s1 = val, s2 = val * val;
#pragma unroll
            for (int m = 32; m >= 1; m >>= 1) {
                s1 += __shfl_xor(s1, m);
                s2 += __shfl_xor(s2, m);
            }
            if ((tid & 63) == 0) {
                red[(tid >> 6) * 2]     = s1;
                red[(tid >> 6) * 2 + 1] = s2;
            }
        }
        __syncthreads();
        if (tid < 128) {
            float mean = (red[0] + red[2]) * (1.0f / 128.0f);
            float var  = (red[1] + red[3]) * (1.0f / 128.0f) - mean * mean;
            float rstd = rsqrtf(fmaxf(var, 0.0f) + 1e-5f);
            hv1_out[bn * CC + tid] = gamma[tid] * (val - mean) * rstd + beta[tid];
        }
    } else {
        // S = hE + msg (fp32, aliases A0 -- safe: A0 unread since GEMM1 barrier)
#pragma unroll
        for (int mt = 0; mt < 3; ++mt)
#pragma unroll
            for (int r = 0; r < 4; ++r) {
                int row = mt * 16 + q * 4 + r;
                S[row * 132 + col0] = hE[(bn * KE + row) * CC + col0] + acc3[mt][0][r] + bc0;
                S[row * 132 + col1] = hE[(bn * KE + row) * CC + col1] + acc3[mt][1][r] + bc1;
            }
        __syncthreads();
        // per-edge-row LayerNorm; 8 groups of 32 lanes, 6 rows each
        int g = tid >> 5, l32 = tid & 31;
        for (int r = g; r < 48; r += 8) {
            float x0 = S[r * 132 + l32];
            float x1 = S[r * 132 + l32 + 32];
            float x2 = S[r * 132 + l32 + 64];
            float x3 = S[r * 132 + l32 + 96];
            float s1 = x0 + x1 + x2 + x3;
            float s2 = x0 * x0 + x1 * x1 + x2 * x2 + x3 * x3;
#pragma unroll
            for (int m = 16; m >= 1; m >>= 1) {
                s1 += __shfl_xor(s1, m, 32);
                s2 += __shfl_xor(s2, m, 32);
            }
            float mean = s1 * (1.0f / 128.0f);
            float var  = s2 * (1.0f / 128.0f) - mean * mean;
            float rstd = rsqrtf(fmaxf(var, 0.0f) + 1e-5f);
            float* orow = hE_out + (bn * KE + r) * CC;
            orow[l32]      = gamma[l32] * (x0 - mean) * rstd + beta[l32];
            orow[l32 + 32] = gamma[l32 + 32] * (x1 - mean) * rstd + beta[l32 + 32];
            orow[l32 + 64] = gamma[l32 + 64] * (x2 - mean) * rstd + beta[l32 + 64];
            orow[l32 + 96] = gamma[l32 + 96] * (x3 - mean) * rstd + beta[l32 + 96];
        }
    }
}

// ---------------------------------------------------------------------------
// MFMA FFN: 16 nodes per block (grid 256, 256 thr = 4 waves).
// hv2 = maskV * LN2(hv + GELU(hv@Win+bin)@Wout+bout), in-place on hv (d_out hV).
// GEMM1: [16x128]@WinT' -> wave w computes cols [128w,128w+128) (8 ntiles).
// GEMM2: [16x512]@WoutT' -> wave w computes cols [32w,32w+32) (2 ntiles).
// Validated numerically in R3 (output 0 passed).
// ---------------------------------------------------------------------------
__global__ __launch_bounds__(256) void ffn_kernel(
    float* __restrict__ hv, const short* __restrict__ WinT,
    const float* __restrict__ Winb, const short* __restrict__ WoutT,
    const float* __restrict__ Woutb, const float* __restrict__ g2,
    const float* __restrict__ b2, const float* __restrict__ maskV) {
    __shared__ __align__(16) float hvF[16 * 132];   // fp32 residual / LN buffer
    __shared__ __align__(16) short Abf[16 * 136];   // bf16 A for GEMM1
    __shared__ __align__(16) short Xs[16 * 520];    // bf16 hidden for GEMM2

    const int tid = threadIdx.x;
    const int bn  = blockIdx.x;       // node tile: nodes [bn*16, bn*16+16)
    const int wave = tid >> 6, lane = tid & 63, q = lane >> 4, m16 = lane & 15;

    // ---- stage hv tile: fp32 copy + bf16 copy ----
    for (int i = tid; i < 512; i += 256) {          // 512 float4 chunks
        int row = i >> 5;                            // 32 chunks/row
        int c4  = (i & 31) * 4;
        float4 v = *(const float4*)(hv + (bn * 16 + row) * CC + c4);
        hvF[row * 132 + c4]     = v.x;
        hvF[row * 132 + c4 + 1] = v.y;
        hvF[row * 132 + c4 + 2] = v.z;
        hvF[row * 132 + c4 + 3] = v.w;
        Abf[row * 136 + c4]     = f2bs(v.x);
        Abf[row * 136 + c4 + 1] = f2bs(v.y);
        Abf[row * 136 + c4 + 2] = f2bs(v.z);
        Abf[row * 136 + c4 + 3] = f2bs(v.w);
    }
    __syncthreads();

    // ---- GEMM1: hidden cols [128w, 128w+128) ----
    fx4 acc1[8];
#pragma unroll
    for (int nt = 0; nt < 8; ++nt)
#pragma unroll
        for (int r = 0; r < 4; ++r) acc1[nt][r] = 0.0f;

#pragma unroll
    for (int kk = 0; kk < 4; ++kk) {
        sx8 af = *(const sx8*)(Abf + m16 * 136 + kk * 32 + q * 8);
#pragma unroll
        for (int nt = 0; nt < 8; ++nt) {
            int coln = wave * 128 + nt * 16 + m16;
            sx8 bf = *(const sx8*)(WinT + coln * CC + kk * 32 + q * 8);
            acc1[nt] = __builtin_amdgcn_mfma_f32_16x16x32_bf16(af, bf, acc1[nt], 0, 0, 0);
        }
    }
#pragma unroll
    for (int nt = 0; nt < 8; ++nt) {
        int coln = wave * 128 + nt * 16 + m16;
        float bi = Winb[coln];
#pragma unroll
        for (int r = 0; r < 4; ++r) {
            int row = q * 4 + r;
            Xs[row * 520 + coln] = f2bs(gelu_f(acc1[nt][r] + bi));
        }
    }
    __syncthreads();

    // ---- GEMM2: out cols [32w, 32w+32) ----
    const int col0 = wave * 32 + m16, col1 = col0 + 16;
    fx4 o0, o1;
#pragma unroll
    for (int r = 0; r < 4; ++r) { o0[r] = 0.0f; o1[r] = 0.0f; }
#pragma unroll
    for (int kk = 0; kk < 16; ++kk) {
        sx8 af = *(const sx8*)(Xs + m16 * 520 + kk * 32 + q * 8);
        sx8 b0 = *(const sx8*)(WoutT + col0 * FFD + kk * 32 + q * 8);
        sx8 b1 = *(const sx8*)(WoutT + col1 * FFD + kk * 32 + q * 8);
        o0 = __builtin_amdgcn_mfma_f32_16x16x32_bf16(af, b0, o0, 0, 0, 0);
        o1 = __builtin_amdgcn_mfma_f32_16x16x32_bf16(af, b1, o1, 0, 0, 0);
    }
    {
        float bo0 = Woutb[col0], bo1 = Woutb[col1];
#pragma unroll
        for (int r = 0; r < 4; ++r) {
            int row = q * 4 + r;
            hvF[row * 132 + col0] += o0[r] + bo0;
            hvF[row * 132 + col1] += o1[r] + bo1;
        }
    }
    __syncthreads();

    // ---- per-node LN2 + mask, write back ----
    int g = tid >> 5, l32 = tid & 31;
#pragma unroll
    for (int rr = 0; rr < 2; ++rr) {
        int row = g + rr * 8;
        float x0 = hvF[row * 132 + l32];
        float x1 = hvF[row * 132 + l32 + 32];
        float x2 = hvF[row * 132 + l32 + 64];
        float x3 = hvF[row * 132 + l32 + 96];
        float s1 = x0 + x1 + x2 + x3;
        float s2 = x0 * x0 + x1 * x1 + x2 * x2 + x3 * x3;
#pragma unroll
        for (int m = 16; m >= 1; m >>= 1) {
            s1 += __shfl_xor(s1, m, 32);
            s2 += __shfl_xor(s2, m, 32);
        }
        float mean = s1 * (1.0f / 128.0f);
        float var  = s2 * (1.0f / 128.0f) - mean * mean;
        float rstd = rsqrtf(fmaxf(var, 0.0f) + 1e-5f);
        int node = bn * 16 + row;
        float mk = maskV[node];
        float* orow = hv + node * CC;
        orow[l32]      = mk * (g2[l32] * (x0 - mean) * rstd + b2[l32]);
        orow[l32 + 32] = mk * (g2[l32 + 32] * (x1 - mean) * rstd + b2[l32 + 32]);
        orow[l32 + 64] = mk * (g2[l32 + 64] * (x2 - mean) * rstd + b2[l32 + 64]);
        orow[l32 + 96] = mk * (g2[l32 + 96] * (x3 - mean) * rstd + b2[l32 + 96]);
    }
}

extern "C" void kernel_launch(void* const* d_in, const int* in_sizes, int n_in,
                              void* d_out, int out_size, void* d_ws, size_t ws_size,
                              hipStream_t stream) {
    (void)in_sizes; (void)n_in; (void)out_size; (void)ws_size;
    const float* hV    = (const float*)d_in[0];
    const float* hE    = (const float*)d_in[1];
    const int*   Eidx  = (const int*)d_in[2];
    const float* maskV = (const float*)d_in[3];
    const float* maskA = (const float*)d_in[4];
    const float* W1w  = (const float*)d_in[5];
    const float* W1b  = (const float*)d_in[6];
    const float* W2w  = (const float*)d_in[7];
    const float* W2b  = (const float*)d_in[8];
    const float* W3w  = (const float*)d_in[9];
    const float* W3b  = (const float*)d_in[10];
    const float* W11w = (const float*)d_in[11];
    const float* W11b = (const float*)d_in[12];
    const float* W12w = (const float*)d_in[13];
    const float* W12b = (const float*)d_in[14];
    const float* W13w = (const float*)d_in[15];
    const float* W13b = (const float*)d_in[16];
    const float* Winw = (const float*)d_in[17];
    const float* Winb = (const float*)d_in[18];
    const float* Woutw = (const float*)d_in[19];
    const float* Woutb = (const float*)d_in[20];
    const float* g1 = (const float*)d_in[21];
    const float* b1 = (const float*)d_in[22];
    const float* g2 = (const float*)d_in[23];
    const float* b2 = (const float*)d_in[24];
    const float* g3 = (const float*)d_in[25];
    const float* b3 = (const float*)d_in[26];

    short* wt   = (short*)d_ws;                 // 294912 bf16 = 576KB
    float* outV = (float*)d_out;                // h_V region [4096,128]
    float* outE = outV + (size_t)BB * NN * CC;  // h_E region [4096,48,128]

    prep_weights<<<1152, 256, 0, stream>>>(W1w, W2w, W3w, W11w, W12w, W13w, Winw, Woutw, wt);
    edge_pass<1><<<BB * NN, 256, 0, stream>>>(hV, hE, Eidx,
                                              wt, W1b, wt + 49152, W2b, wt + 65536, W3b,
                                              maskA, outV, g1, b1, nullptr);
    ffn_kernel<<<256, 256, 0, stream>>>(outV, wt + 163840, Winb, wt + 229376, Woutb, g2, b2, maskV);
    edge_pass<2><<<BB * NN, 256, 0, stream>>>(outV, hE, Eidx,
                                              wt + 81920, W11b, wt + 131072, W12b, wt + 147456, W13b,
                                              nullptr, nullptr, g3, b3, outE);
}